// Round 4
// baseline (648.305 us; speedup 1.0000x reference)
//
#include <hip/hip_runtime.h>
#include <math.h>

#define NN 20000
#define EE 320000
#define ETOT (EE + NN)
#define NEG 0.2f

typedef unsigned short ushortT;
typedef __attribute__((ext_vector_type(8))) short short8v;       // 8 bf16 (4 VGPRs)
typedef __attribute__((ext_vector_type(8))) unsigned short u16x8;
typedef __attribute__((ext_vector_type(4))) float f32x4;

// ---------- helpers ----------
__device__ __forceinline__ ushortT f2b(float f){            // fp32 -> bf16 (RNE)
  unsigned u = __float_as_uint(f);
  u += 0x7FFFu + ((u >> 16) & 1u);
  return (ushortT)(u >> 16);
}
__device__ __forceinline__ float b2f(ushortT b){
  return __uint_as_float(((unsigned)b) << 16);
}

// ---------- conversions ----------
__global__ void k_cvt(const float* __restrict__ in, ushortT* __restrict__ outp, int n4){
  int i = blockIdx.x*blockDim.x + threadIdx.x;
  if(i < n4){
    float4 v = *reinterpret_cast<const float4*>(in + (size_t)i*4);
    ushort4 o;
    o.x = f2b(v.x); o.y = f2b(v.y); o.z = f2b(v.z); o.w = f2b(v.w);
    *reinterpret_cast<ushort4*>(outp + (size_t)i*4) = o;
  }
}

// W[k][n] 512x512 fp32 -> Wt[n][k] bf16
__global__ void k_wtrans(const float* __restrict__ W, ushortT* __restrict__ Wt){
  __shared__ float t[32][33];
  int bk = blockIdx.x*32, bn = blockIdx.y*32;
  int tx = threadIdx.x & 31, ty = threadIdx.x >> 5;
  for(int r=0;r<32;r+=8)
    t[ty+r][tx] = W[(size_t)(bk+ty+r)*512 + bn+tx];
  __syncthreads();
  for(int r=0;r<32;r+=8)
    Wt[(size_t)(bn+ty+r)*512 + bk+tx] = f2b(t[tx][ty+r]);
}

// ---------- CSR build ----------
__global__ void k_count(const int* __restrict__ edst, int* __restrict__ counts){
  int e = blockIdx.x*blockDim.x + threadIdx.x;
  if(e < ETOT){
    int d = (e < EE) ? edst[e] : (e - EE);
    atomicAdd(&counts[d], 1);
  }
}

__global__ void k_scan(const int* __restrict__ counts, int* __restrict__ rowstart){
  __shared__ int lds[1024];
  int tid = threadIdx.x;
  int base = tid*20;
  int s = 0;
  for(int j=0;j<20;j++){ int i=base+j; if(i<NN) s += counts[i]; }
  lds[tid] = s; __syncthreads();
  for(int off=1; off<1024; off<<=1){
    int v = (tid>=off) ? lds[tid-off] : 0;
    __syncthreads();
    lds[tid] += v;
    __syncthreads();
  }
  int run = lds[tid] - s;
  for(int j=0;j<20;j++){
    int i = base+j;
    if(i <= NN){
      rowstart[i] = run;
      if(i < NN) run += counts[i];
    }
  }
}

__global__ void k_fill(const int* __restrict__ esrc, const int* __restrict__ edst,
                       const int* __restrict__ rowstart,
                       int* __restrict__ cursor, int* __restrict__ srcs,
                       int* __restrict__ epos){
  int e = blockIdx.x*blockDim.x + threadIdx.x;
  if(e < ETOT){
    int d = (e < EE) ? edst[e] : (e - EE);
    int s = (e < EE) ? esrc[e] : (e - EE);
    int pos = rowstart[d] + atomicAdd(&cursor[d], 1);
    srcs[pos] = s;
    epos[e] = pos;
  }
}

// ---------- bf16 MFMA GEMM: C[M,512] = A[M,512] @ Bt[512,512]^T, bf16 out ----------
__global__ __launch_bounds__(256) void k_gemm_bf16(
    const ushortT* __restrict__ A, const ushortT* __restrict__ Bt,
    ushortT* __restrict__ Cb, int M)
{
  const int K = 512;
  __shared__ __align__(16) ushortT As[128*32];
  __shared__ __align__(16) ushortT Bs[128*32];
  int bm = blockIdx.x*128, bn = blockIdx.y*128;
  int tid = threadIdx.x, wave = tid>>6, lane = tid&63;
  int wm = (wave>>1)*64, wn = (wave&1)*64;
  f32x4 acc[4][4] = {};

  int l4 = lane>>2;
  int s4 = lane&3;
  int src_slot = s4 ^ (l4 & 3);     // XOR swizzle (both-sides involution)
  int r16 = lane&15, kg = lane>>4;

  for(int k0=0;k0<K;k0+=32){
    #pragma unroll
    for(int c=0;c<2;c++){
      int chunk = wave*2 + c;
      int arow = bm + chunk*16 + l4; if(arow > M-1) arow = M-1;
      const ushortT* ga = A + (size_t)arow*K + k0 + src_slot*8;
      __builtin_amdgcn_global_load_lds(
          (const __attribute__((address_space(1))) void*)ga,
          (__attribute__((address_space(3))) void*)(As + chunk*16*32), 16, 0, 0);
      int brow = bn + chunk*16 + l4;
      const ushortT* gb = Bt + (size_t)brow*K + k0 + src_slot*8;
      __builtin_amdgcn_global_load_lds(
          (const __attribute__((address_space(1))) void*)gb,
          (__attribute__((address_space(3))) void*)(Bs + chunk*16*32), 16, 0, 0);
    }
    asm volatile("s_waitcnt vmcnt(0)");
    __syncthreads();

    short8v a_frag[4], b_frag[4];
    #pragma unroll
    for(int i=0;i<4;i++){
      int row = wm + i*16 + r16;
      a_frag[i] = *reinterpret_cast<const short8v*>(As + row*32 + ((kg ^ (row&3))<<3));
    }
    #pragma unroll
    for(int j=0;j<4;j++){
      int row = wn + j*16 + r16;
      b_frag[j] = *reinterpret_cast<const short8v*>(Bs + row*32 + ((kg ^ (row&3))<<3));
    }
    #pragma unroll
    for(int i=0;i<4;i++)
      #pragma unroll
      for(int j=0;j<4;j++)
        acc[i][j] = __builtin_amdgcn_mfma_f32_16x16x32_bf16(a_frag[i], b_frag[j], acc[i][j], 0, 0, 0);
    __syncthreads();
  }

  // C/D layout: col = lane&15, row = (lane>>4)*4 + reg
  #pragma unroll
  for(int i=0;i<4;i++){
    #pragma unroll
    for(int j=0;j<4;j++){
      #pragma unroll
      for(int r=0;r<4;r++){
        int row = bm + wm + i*16 + kg*4 + r;
        int col = bn + wn + j*16 + r16;
        if(row < M) Cb[(size_t)row*512 + col] = f2b(acc[i][j][r]);
      }
    }
  }
}

// ---------- fp32 GEMM, bf16 A: C[M,Nc] = A[M,512] @ B[512,Nc] (layer 3) ----------
__global__ __launch_bounds__(256) void k_gemm3(const ushortT* __restrict__ A,
                                               const float* __restrict__ B,
                                               float* __restrict__ C,
                                               int M, int Nc){
  __shared__ __align__(16) float As[16][64];
  __shared__ __align__(16) float Bs[16][64];
  const int K = 512;
  int bm = blockIdx.x*64, bn = blockIdx.y*64;
  int tid = threadIdx.x;
  int tm = tid>>4, tn = tid&15;
  int lam = tid>>2, lak = (tid&3)<<2;
  int lbk = tid>>4, lbn = (tid&15)<<2;
  float acc[4][4] = {};
  for(int k0=0;k0<K;k0+=16){
    int gm = bm + lam;
    float a0=0.f,a1=0.f,a2=0.f,a3=0.f;
    if(gm < M){
      ushort4 a4 = *reinterpret_cast<const ushort4*>(A + (size_t)gm*K + k0 + lak);
      a0=b2f(a4.x); a1=b2f(a4.y); a2=b2f(a4.z); a3=b2f(a4.w);
    }
    As[lak+0][lam]=a0; As[lak+1][lam]=a1; As[lak+2][lam]=a2; As[lak+3][lam]=a3;

    int gk = k0 + lbk;
    int gn = bn + lbn;
    float4 b;
    if(gn + 3 < Nc){
      b = *reinterpret_cast<const float4*>(B + (size_t)gk*Nc + gn);
    } else {
      b.x = (gn+0<Nc)? B[(size_t)gk*Nc+gn+0] : 0.f;
      b.y = (gn+1<Nc)? B[(size_t)gk*Nc+gn+1] : 0.f;
      b.z = (gn+2<Nc)? B[(size_t)gk*Nc+gn+2] : 0.f;
      b.w = (gn+3<Nc)? B[(size_t)gk*Nc+gn+3] : 0.f;
    }
    *reinterpret_cast<float4*>(&Bs[lbk][lbn]) = b;
    __syncthreads();
    #pragma unroll
    for(int kk=0;kk<16;kk++){
      float4 av = *reinterpret_cast<const float4*>(&As[kk][tm<<2]);
      float4 bv = *reinterpret_cast<const float4*>(&Bs[kk][tn<<2]);
      float aa[4] = {av.x, av.y, av.z, av.w};
      float bb[4] = {bv.x, bv.y, bv.z, bv.w};
      #pragma unroll
      for(int i=0;i<4;i++)
        #pragma unroll
        for(int j=0;j<4;j++)
          acc[i][j] += aa[i]*bb[j];
    }
    __syncthreads();
  }
  #pragma unroll
  for(int i=0;i<4;i++){
    int r = bm + (tm<<2) + i;
    if(r < M){
      #pragma unroll
      for(int j=0;j<4;j++){
        int c = bn + (tn<<2) + j;
        if(c < Nc) C[(size_t)r*Nc + c] = acc[i][j];
      }
    }
  }
}

// ---------- per-node attention coefficients (bf16 features) ----------
template<int H, int C>
__global__ void k_attn_b(const ushortT* __restrict__ feat, const float* __restrict__ atts,
                         const float* __restrict__ attd, float* __restrict__ a_s,
                         float* __restrict__ a_d){
  int n = blockIdx.x*4 + (threadIdx.x>>6);
  int lane = threadIdx.x & 63;
  if(n >= NN) return;
  #pragma unroll
  for(int h=0;h<H;h++){
    float s1 = 0.f, s2 = 0.f;
    if(lane < C){
      float v = b2f(feat[(size_t)n*(H*C) + h*C + lane]);
      s1 = v*atts[h*C+lane];
      s2 = v*attd[h*C+lane];
    }
    for(int off=32; off; off>>=1){
      s1 += __shfl_xor(s1, off);
      s2 += __shfl_xor(s2, off);
    }
    if(lane == 0){ a_s[n*H+h] = s1; a_d[n*H+h] = s2; }
  }
}

// fp32 features (layer 3)
template<int H, int C>
__global__ void k_attn_f(const float* __restrict__ feat, const float* __restrict__ atts,
                         const float* __restrict__ attd, float* __restrict__ a_s,
                         float* __restrict__ a_d){
  int n = blockIdx.x*4 + (threadIdx.x>>6);
  int lane = threadIdx.x & 63;
  if(n >= NN) return;
  #pragma unroll
  for(int h=0;h<H;h++){
    float s1 = 0.f, s2 = 0.f;
    if(lane < C){
      float v = feat[(size_t)n*(H*C) + h*C + lane];
      s1 = v*atts[h*C+lane];
      s2 = v*attd[h*C+lane];
    }
    for(int off=32; off; off>>=1){
      s1 += __shfl_xor(s1, off);
      s2 += __shfl_xor(s2, off);
    }
    if(lane == 0){ a_s[n*H+h] = s1; a_d[n*H+h] = s2; }
  }
}

// ---------- fused edge kernel: one THREAD per edge, all heads vectorized ----------
// softmax is shift-invariant; logits are O(10) here so exp() cannot overflow fp32.
__global__ void k_edge8(const int* __restrict__ esrc, const int* __restrict__ edst,
                        const int* __restrict__ epos,
                        const float* __restrict__ a_s, const float* __restrict__ a_d,
                        float* __restrict__ exc, float* __restrict__ den){
  int e = blockIdx.x*blockDim.x + threadIdx.x;
  if(e >= ETOT) return;
  int s = (e < EE) ? esrc[e] : (e - EE);
  int d = (e < EE) ? edst[e] : (e - EE);
  int pos = epos[e];
  float4 s0 = *reinterpret_cast<const float4*>(a_s + (size_t)s*8);
  float4 s1 = *reinterpret_cast<const float4*>(a_s + (size_t)s*8 + 4);
  float4 d0 = *reinterpret_cast<const float4*>(a_d + (size_t)d*8);
  float4 d1 = *reinterpret_cast<const float4*>(a_d + (size_t)d*8 + 4);
  float l[8] = { s0.x+d0.x, s0.y+d0.y, s0.z+d0.z, s0.w+d0.w,
                 s1.x+d1.x, s1.y+d1.y, s1.z+d1.z, s1.w+d1.w };
  float ex[8];
  #pragma unroll
  for(int h=0;h<8;h++){
    float v = l[h];
    v = (v > 0.f) ? v : NEG*v;
    ex[h] = expf(v);
  }
  float4 e0 = make_float4(ex[0],ex[1],ex[2],ex[3]);
  float4 e1 = make_float4(ex[4],ex[5],ex[6],ex[7]);
  *reinterpret_cast<float4*>(exc + (size_t)pos*8)     = e0;
  *reinterpret_cast<float4*>(exc + (size_t)pos*8 + 4) = e1;
  #pragma unroll
  for(int h=0;h<8;h++) atomicAdd(&den[d*8+h], ex[h]);
}

__global__ void k_edge1(const int* __restrict__ esrc, const int* __restrict__ edst,
                        const int* __restrict__ epos,
                        const float* __restrict__ a_s, const float* __restrict__ a_d,
                        float* __restrict__ exc, float* __restrict__ den){
  int e = blockIdx.x*blockDim.x + threadIdx.x;
  if(e >= ETOT) return;
  int s = (e < EE) ? esrc[e] : (e - EE);
  int d = (e < EE) ? edst[e] : (e - EE);
  float l = a_s[s] + a_d[d];
  l = (l > 0.f) ? l : NEG*l;
  float ex = expf(l);
  exc[epos[e]] = ex;
  atomicAdd(&den[d], ex);
}

// ---------- CSR gather-aggregate (H=8,C=64): one WAVE per dst, 4-deep pipeline ----------
__global__ __launch_bounds__(256) void k_agg512(const ushortT* __restrict__ feat,
    const float* __restrict__ exc, const float* __restrict__ den,
    const int* __restrict__ rowstart, const int* __restrict__ srcs,
    const float* __restrict__ bias, ushortT* __restrict__ outb){
  int d = blockIdx.x*4 + (threadIdx.x>>6);
  int lane = threadIdx.x & 63;
  int c0 = lane*8;                  // 8 contiguous channels per lane
  int head = lane>>3;
  float acc[8] = {0.f,0.f,0.f,0.f,0.f,0.f,0.f,0.f};
  int p0 = rowstart[d], p1 = rowstart[d+1];
  int p = p0;
  // 4-deep software pipeline: 4 independent gathers in flight
  for(; p+4 <= p1; p += 4){
    int s0_ = srcs[p], s1_ = srcs[p+1], s2_ = srcs[p+2], s3_ = srcs[p+3];
    float al0 = exc[(size_t)(p+0)*8 + head];
    float al1 = exc[(size_t)(p+1)*8 + head];
    float al2 = exc[(size_t)(p+2)*8 + head];
    float al3 = exc[(size_t)(p+3)*8 + head];
    u16x8 v0 = *reinterpret_cast<const u16x8*>(feat + (size_t)s0_*512 + c0);
    u16x8 v1 = *reinterpret_cast<const u16x8*>(feat + (size_t)s1_*512 + c0);
    u16x8 v2 = *reinterpret_cast<const u16x8*>(feat + (size_t)s2_*512 + c0);
    u16x8 v3 = *reinterpret_cast<const u16x8*>(feat + (size_t)s3_*512 + c0);
    #pragma unroll
    for(int j=0;j<8;j++) acc[j] += al0*b2f((ushortT)v0[j]);
    #pragma unroll
    for(int j=0;j<8;j++) acc[j] += al1*b2f((ushortT)v1[j]);
    #pragma unroll
    for(int j=0;j<8;j++) acc[j] += al2*b2f((ushortT)v2[j]);
    #pragma unroll
    for(int j=0;j<8;j++) acc[j] += al3*b2f((ushortT)v3[j]);
  }
  for(; p<p1; p++){
    int s_ = srcs[p];
    float al = exc[(size_t)p*8 + head];
    u16x8 v = *reinterpret_cast<const u16x8*>(feat + (size_t)s_*512 + c0);
    #pragma unroll
    for(int j=0;j<8;j++) acc[j] += al*b2f((ushortT)v[j]);
  }
  float invd = 1.f/(den[d*8+head] + 1e-16f);
  u16x8 ov;
  #pragma unroll
  for(int j=0;j<8;j++){
    float o = acc[j]*invd + bias[c0+j];
    o = (o > 0.f) ? o : (expf(o) - 1.f);
    ov[j] = f2b(o);
  }
  *reinterpret_cast<u16x8*>(outb + (size_t)d*512 + c0) = ov;
}

// ---------- layer-3 aggregate (H=1,C=40) + bias + log_softmax ----------
__global__ void k_agg_l3(const float* __restrict__ feat,
    const float* __restrict__ exc, const float* __restrict__ den,
    const int* __restrict__ rowstart, const int* __restrict__ srcs,
    const float* __restrict__ bias, float* __restrict__ outp){
  int d = blockIdx.x;
  int lane = threadIdx.x;       // 64 threads
  bool act = lane < 40;
  int li = act ? lane : 0;
  float acc = 0.f;
  int p0 = rowstart[d], p1 = rowstart[d+1];
  int p = p0;
  for(; p+4 <= p1; p += 4){
    int s0_ = srcs[p], s1_ = srcs[p+1], s2_ = srcs[p+2], s3_ = srcs[p+3];
    float al0 = exc[p+0], al1 = exc[p+1], al2 = exc[p+2], al3 = exc[p+3];
    float v0 = feat[(size_t)s0_*40 + li];
    float v1 = feat[(size_t)s1_*40 + li];
    float v2 = feat[(size_t)s2_*40 + li];
    float v3 = feat[(size_t)s3_*40 + li];
    acc += al0*v0 + al1*v1 + al2*v2 + al3*v3;
  }
  for(; p<p1; p++){
    acc += exc[p]*feat[(size_t)srcs[p]*40 + li];
  }
  float invd = 1.f/(den[d] + 1e-16f);
  float o = act ? (acc*invd + bias[lane]) : -1e30f;
  float m = o;
  for(int off=32; off; off>>=1) m = fmaxf(m, __shfl_xor(m, off));
  float e_ = act ? expf(o - m) : 0.f;
  float ssum = e_;
  for(int off=32; off; off>>=1) ssum += __shfl_xor(ssum, off);
  if(act) outp[(size_t)d*40 + lane] = o - m - logf(ssum);
}

extern "C" void kernel_launch(void* const* d_in, const int* in_sizes, int n_in,
                              void* d_out, int out_size, void* d_ws, size_t ws_size,
                              hipStream_t stream){
  const float* x   = (const float*)d_in[0];
  const int*   ei  = (const int*)d_in[1];
  const int*   esrc = ei;
  const int*   edst = ei + EE;
  const float* W1  = (const float*)d_in[2];
  const float* as1 = (const float*)d_in[3];
  const float* ad1 = (const float*)d_in[4];
  const float* b1  = (const float*)d_in[5];
  const float* W2  = (const float*)d_in[6];
  const float* as2 = (const float*)d_in[7];
  const float* ad2 = (const float*)d_in[8];
  const float* b2  = (const float*)d_in[9];
  const float* W3  = (const float*)d_in[10];
  const float* as3 = (const float*)d_in[11];
  const float* ad3 = (const float*)d_in[12];
  const float* b3  = (const float*)d_in[13];
  float* out = (float*)d_out;

  char* w = (char*)d_ws;
  size_t off = 0;
  auto alloc = [&](size_t bytes)->char*{
    char* p = w + off;
    off = (off + bytes + 255) & ~(size_t)255;
    return p;
  };
  ushortT*  xb   = (ushortT*)alloc((size_t)NN*512*2);
  ushortT*  fA   = (ushortT*)alloc((size_t)NN*512*2);
  ushortT*  fB   = (ushortT*)alloc((size_t)NN*512*2);
  float*    h3   = (float*)alloc((size_t)NN*40*4);
  ushortT*  Wt1  = (ushortT*)alloc((size_t)512*512*2);
  ushortT*  Wt2  = (ushortT*)alloc((size_t)512*512*2);
  float*    a_s  = (float*)alloc((size_t)NN*8*4);
  float*    a_d  = (float*)alloc((size_t)NN*8*4);
  float*    den  = (float*)alloc((size_t)NN*8*4);
  float*    exc  = (float*)alloc((size_t)ETOT*8*4);
  int* rowstart  = (int*)alloc((size_t)(NN+1)*4);
  int* cursor    = (int*)alloc((size_t)NN*4);
  int* counts    = (int*)alloc((size_t)NN*4);
  int* srcs      = (int*)alloc((size_t)ETOT*4);
  int* epos      = (int*)alloc((size_t)ETOT*4);

  // ---- conversions (independent of CSR) ----
  k_cvt<<<(NN*512/4 + 255)/256, 256, 0, stream>>>(x, xb, NN*512/4);
  dim3 wt_grid(16, 16);
  k_wtrans<<<wt_grid, 256, 0, stream>>>(W1, Wt1);
  k_wtrans<<<wt_grid, 256, 0, stream>>>(W2, Wt2);

  // ---- CSR build (dst-grouped) ----
  hipMemsetAsync(counts, 0, (size_t)NN*4, stream);
  hipMemsetAsync(cursor, 0, (size_t)NN*4, stream);
  k_count<<<(ETOT+255)/256, 256, 0, stream>>>(edst, counts);
  k_scan<<<1, 1024, 0, stream>>>(counts, rowstart);
  k_fill<<<(ETOT+255)/256, 256, 0, stream>>>(esrc, edst, rowstart, cursor, srcs, epos);

  dim3 mgrid((NN+127)/128, 4);
  int edge_blocks = (ETOT + 255)/256;

  // ---- layer 1 ----
  k_gemm_bf16<<<mgrid, 256, 0, stream>>>(xb, Wt1, fA, NN);
  k_attn_b<8,64><<<(NN+3)/4, 256, 0, stream>>>(fA, as1, ad1, a_s, a_d);
  hipMemsetAsync(den, 0, (size_t)NN*8*4, stream);
  k_edge8<<<edge_blocks, 256, 0, stream>>>(esrc, edst, epos, a_s, a_d, exc, den);
  k_agg512<<<NN/4, 256, 0, stream>>>(fA, exc, den, rowstart, srcs, b1, fB);

  // ---- layer 2 ----
  k_gemm_bf16<<<mgrid, 256, 0, stream>>>(fB, Wt2, fA, NN);
  k_attn_b<8,64><<<(NN+3)/4, 256, 0, stream>>>(fA, as2, ad2, a_s, a_d);
  hipMemsetAsync(den, 0, (size_t)NN*8*4, stream);
  k_edge8<<<edge_blocks, 256, 0, stream>>>(esrc, edst, epos, a_s, a_d, exc, den);
  k_agg512<<<NN/4, 256, 0, stream>>>(fA, exc, den, rowstart, srcs, b2, fB);

  // ---- layer 3 ----
  dim3 gemm_grid3((NN+63)/64, 1);
  k_gemm3<<<gemm_grid3, 256, 0, stream>>>(fB, W3, h3, NN, 40);
  k_attn_f<1,40><<<(NN+3)/4, 256, 0, stream>>>(h3, as3, ad3, a_s, a_d);
  hipMemsetAsync(den, 0, (size_t)NN*4, stream);
  k_edge1<<<edge_blocks, 256, 0, stream>>>(esrc, edst, epos, a_s, a_d, exc, den);
  k_agg_l3<<<NN, 64, 0, stream>>>(h3, exc, den, rowstart, srcs, b3, out);
}

// Round 5
// 334.417 us; speedup vs baseline: 1.9386x; 1.9386x over previous
//
#include <hip/hip_runtime.h>
#include <math.h>

#define NN 20000
#define EE 320000
#define ETOT (EE + NN)
#define NEG 0.2f

typedef unsigned short ushortT;
typedef __attribute__((ext_vector_type(8))) short short8v;       // 8 bf16 (4 VGPRs)
typedef __attribute__((ext_vector_type(8))) unsigned short u16x8;
typedef __attribute__((ext_vector_type(4))) float f32x4;

// ---------- helpers ----------
__device__ __forceinline__ ushortT f2b(float f){            // fp32 -> bf16 (RNE)
  unsigned u = __float_as_uint(f);
  u += 0x7FFFu + ((u >> 16) & 1u);
  return (ushortT)(u >> 16);
}
__device__ __forceinline__ float b2f(ushortT b){
  return __uint_as_float(((unsigned)b) << 16);
}

// ---------- conversions ----------
__global__ void k_cvt(const float* __restrict__ in, ushortT* __restrict__ outp, int n4){
  int i = blockIdx.x*blockDim.x + threadIdx.x;
  if(i < n4){
    float4 v = *reinterpret_cast<const float4*>(in + (size_t)i*4);
    ushort4 o;
    o.x = f2b(v.x); o.y = f2b(v.y); o.z = f2b(v.z); o.w = f2b(v.w);
    *reinterpret_cast<ushort4*>(outp + (size_t)i*4) = o;
  }
}

// W[k][n] 512x512 fp32 -> Wt[n][k] bf16
__global__ void k_wtrans(const float* __restrict__ W, ushortT* __restrict__ Wt){
  __shared__ float t[32][33];
  int bk = blockIdx.x*32, bn = blockIdx.y*32;
  int tx = threadIdx.x & 31, ty = threadIdx.x >> 5;
  for(int r=0;r<32;r+=8)
    t[ty+r][tx] = W[(size_t)(bk+ty+r)*512 + bn+tx];
  __syncthreads();
  for(int r=0;r<32;r+=8)
    Wt[(size_t)(bn+ty+r)*512 + bk+tx] = f2b(t[tx][ty+r]);
}

// ---------- CSR build ----------
__global__ void k_count(const int* __restrict__ edst, int* __restrict__ counts){
  int e = blockIdx.x*blockDim.x + threadIdx.x;
  if(e < ETOT){
    int d = (e < EE) ? edst[e] : (e - EE);
    atomicAdd(&counts[d], 1);
  }
}

__global__ void k_scan(const int* __restrict__ counts, int* __restrict__ rowstart){
  __shared__ int lds[1024];
  int tid = threadIdx.x;
  int base = tid*20;
  int s = 0;
  for(int j=0;j<20;j++){ int i=base+j; if(i<NN) s += counts[i]; }
  lds[tid] = s; __syncthreads();
  for(int off=1; off<1024; off<<=1){
    int v = (tid>=off) ? lds[tid-off] : 0;
    __syncthreads();
    lds[tid] += v;
    __syncthreads();
  }
  int run = lds[tid] - s;
  for(int j=0;j<20;j++){
    int i = base+j;
    if(i <= NN){
      rowstart[i] = run;
      if(i < NN) run += counts[i];
    }
  }
}

__global__ void k_fill(const int* __restrict__ esrc, const int* __restrict__ edst,
                       const int* __restrict__ rowstart,
                       int* __restrict__ cursor, int* __restrict__ srcs){
  int e = blockIdx.x*blockDim.x + threadIdx.x;
  if(e < ETOT){
    int d = (e < EE) ? edst[e] : (e - EE);
    int s = (e < EE) ? esrc[e] : (e - EE);
    int pos = rowstart[d] + atomicAdd(&cursor[d], 1);
    srcs[pos] = s;
  }
}

// ---------- bf16 MFMA GEMM: C[M,512] = A[M,512] @ Bt[512,512]^T, bf16 out ----------
__global__ __launch_bounds__(256) void k_gemm_bf16(
    const ushortT* __restrict__ A, const ushortT* __restrict__ Bt,
    ushortT* __restrict__ Cb, int M)
{
  const int K = 512;
  __shared__ __align__(16) ushortT As[128*32];
  __shared__ __align__(16) ushortT Bs[128*32];
  int bm = blockIdx.x*128, bn = blockIdx.y*128;
  int tid = threadIdx.x, wave = tid>>6, lane = tid&63;
  int wm = (wave>>1)*64, wn = (wave&1)*64;
  f32x4 acc[4][4] = {};

  int l4 = lane>>2;
  int s4 = lane&3;
  int src_slot = s4 ^ (l4 & 3);     // XOR swizzle (both-sides involution)
  int r16 = lane&15, kg = lane>>4;

  for(int k0=0;k0<K;k0+=32){
    #pragma unroll
    for(int c=0;c<2;c++){
      int chunk = wave*2 + c;
      int arow = bm + chunk*16 + l4; if(arow > M-1) arow = M-1;
      const ushortT* ga = A + (size_t)arow*K + k0 + src_slot*8;
      __builtin_amdgcn_global_load_lds(
          (const __attribute__((address_space(1))) void*)ga,
          (__attribute__((address_space(3))) void*)(As + chunk*16*32), 16, 0, 0);
      int brow = bn + chunk*16 + l4;
      const ushortT* gb = Bt + (size_t)brow*K + k0 + src_slot*8;
      __builtin_amdgcn_global_load_lds(
          (const __attribute__((address_space(1))) void*)gb,
          (__attribute__((address_space(3))) void*)(Bs + chunk*16*32), 16, 0, 0);
    }
    asm volatile("s_waitcnt vmcnt(0)");
    __syncthreads();

    short8v a_frag[4], b_frag[4];
    #pragma unroll
    for(int i=0;i<4;i++){
      int row = wm + i*16 + r16;
      a_frag[i] = *reinterpret_cast<const short8v*>(As + row*32 + ((kg ^ (row&3))<<3));
    }
    #pragma unroll
    for(int j=0;j<4;j++){
      int row = wn + j*16 + r16;
      b_frag[j] = *reinterpret_cast<const short8v*>(Bs + row*32 + ((kg ^ (row&3))<<3));
    }
    #pragma unroll
    for(int i=0;i<4;i++)
      #pragma unroll
      for(int j=0;j<4;j++)
        acc[i][j] = __builtin_amdgcn_mfma_f32_16x16x32_bf16(a_frag[i], b_frag[j], acc[i][j], 0, 0, 0);
    __syncthreads();
  }

  // C/D layout: col = lane&15, row = (lane>>4)*4 + reg
  #pragma unroll
  for(int i=0;i<4;i++){
    #pragma unroll
    for(int j=0;j<4;j++){
      #pragma unroll
      for(int r=0;r<4;r++){
        int row = bm + wm + i*16 + kg*4 + r;
        int col = bn + wn + j*16 + r16;
        if(row < M) Cb[(size_t)row*512 + col] = f2b(acc[i][j][r]);
      }
    }
  }
}

// ---------- fp32 GEMM, bf16 A: C[M,Nc] = A[M,512] @ B[512,Nc] (layer 3) ----------
__global__ __launch_bounds__(256) void k_gemm3(const ushortT* __restrict__ A,
                                               const float* __restrict__ B,
                                               float* __restrict__ C,
                                               int M, int Nc){
  __shared__ __align__(16) float As[16][64];
  __shared__ __align__(16) float Bs[16][64];
  const int K = 512;
  int bm = blockIdx.x*64, bn = blockIdx.y*64;
  int tid = threadIdx.x;
  int tm = tid>>4, tn = tid&15;
  int lam = tid>>2, lak = (tid&3)<<2;
  int lbk = tid>>4, lbn = (tid&15)<<2;
  float acc[4][4] = {};
  for(int k0=0;k0<K;k0+=16){
    int gm = bm + lam;
    float a0=0.f,a1=0.f,a2=0.f,a3=0.f;
    if(gm < M){
      ushort4 a4 = *reinterpret_cast<const ushort4*>(A + (size_t)gm*K + k0 + lak);
      a0=b2f(a4.x); a1=b2f(a4.y); a2=b2f(a4.z); a3=b2f(a4.w);
    }
    As[lak+0][lam]=a0; As[lak+1][lam]=a1; As[lak+2][lam]=a2; As[lak+3][lam]=a3;

    int gk = k0 + lbk;
    int gn = bn + lbn;
    float4 b;
    if(gn + 3 < Nc){
      b = *reinterpret_cast<const float4*>(B + (size_t)gk*Nc + gn);
    } else {
      b.x = (gn+0<Nc)? B[(size_t)gk*Nc+gn+0] : 0.f;
      b.y = (gn+1<Nc)? B[(size_t)gk*Nc+gn+1] : 0.f;
      b.z = (gn+2<Nc)? B[(size_t)gk*Nc+gn+2] : 0.f;
      b.w = (gn+3<Nc)? B[(size_t)gk*Nc+gn+3] : 0.f;
    }
    *reinterpret_cast<float4*>(&Bs[lbk][lbn]) = b;
    __syncthreads();
    #pragma unroll
    for(int kk=0;kk<16;kk++){
      float4 av = *reinterpret_cast<const float4*>(&As[kk][tm<<2]);
      float4 bv = *reinterpret_cast<const float4*>(&Bs[kk][tn<<2]);
      float aa[4] = {av.x, av.y, av.z, av.w};
      float bb[4] = {bv.x, bv.y, bv.z, bv.w};
      #pragma unroll
      for(int i=0;i<4;i++)
        #pragma unroll
        for(int j=0;j<4;j++)
          acc[i][j] += aa[i]*bb[j];
    }
    __syncthreads();
  }
  #pragma unroll
  for(int i=0;i<4;i++){
    int r = bm + (tm<<2) + i;
    if(r < M){
      #pragma unroll
      for(int j=0;j<4;j++){
        int c = bn + (tn<<2) + j;
        if(c < Nc) C[(size_t)r*Nc + c] = acc[i][j];
      }
    }
  }
}

// ---------- per-node attention coefficients (bf16 features) ----------
template<int H, int C>
__global__ void k_attn_b(const ushortT* __restrict__ feat, const float* __restrict__ atts,
                         const float* __restrict__ attd, float* __restrict__ a_s,
                         float* __restrict__ a_d){
  int n = blockIdx.x*4 + (threadIdx.x>>6);
  int lane = threadIdx.x & 63;
  if(n >= NN) return;
  #pragma unroll
  for(int h=0;h<H;h++){
    float s1 = 0.f, s2 = 0.f;
    if(lane < C){
      float v = b2f(feat[(size_t)n*(H*C) + h*C + lane]);
      s1 = v*atts[h*C+lane];
      s2 = v*attd[h*C+lane];
    }
    for(int off=32; off; off>>=1){
      s1 += __shfl_xor(s1, off);
      s2 += __shfl_xor(s2, off);
    }
    if(lane == 0){ a_s[n*H+h] = s1; a_d[n*H+h] = s2; }
  }
}

// fp32 features (layer 3)
template<int H, int C>
__global__ void k_attn_f(const float* __restrict__ feat, const float* __restrict__ atts,
                         const float* __restrict__ attd, float* __restrict__ a_s,
                         float* __restrict__ a_d){
  int n = blockIdx.x*4 + (threadIdx.x>>6);
  int lane = threadIdx.x & 63;
  if(n >= NN) return;
  #pragma unroll
  for(int h=0;h<H;h++){
    float s1 = 0.f, s2 = 0.f;
    if(lane < C){
      float v = feat[(size_t)n*(H*C) + h*C + lane];
      s1 = v*atts[h*C+lane];
      s2 = v*attd[h*C+lane];
    }
    for(int off=32; off; off>>=1){
      s1 += __shfl_xor(s1, off);
      s2 += __shfl_xor(s2, off);
    }
    if(lane == 0){ a_s[n*H+h] = s1; a_d[n*H+h] = s2; }
  }
}

// ---------- fused CSR aggregate (H=8,C=64): softmax computed on the fly ----------
// one WAVE per dst; lane owns 8 contiguous channels; head = lane>>3.
// al = exp(leaky(a_s[s]+a_d[d])) computed in-loop; denominator accumulated
// in-register (no global atomics, no edge kernel, no exc buffer).
__global__ __launch_bounds__(256) void k_agg512(const ushortT* __restrict__ feat,
    const float* __restrict__ a_s, const float* __restrict__ a_d,
    const int* __restrict__ rowstart, const int* __restrict__ srcs,
    const float* __restrict__ bias, ushortT* __restrict__ outb){
  int d = blockIdx.x*4 + (threadIdx.x>>6);
  int lane = threadIdx.x & 63;
  int c0 = lane*8;
  int head = lane>>3;
  float ad_h = a_d[(size_t)d*8 + head];          // row-constant
  float acc[8] = {0.f,0.f,0.f,0.f,0.f,0.f,0.f,0.f};
  float dsum = 0.f;
  int p0 = rowstart[d], p1 = rowstart[d+1];
  int p = p0;
  // 4-deep software pipeline: independent gathers in flight
  for(; p+4 <= p1; p += 4){
    int s0_ = srcs[p], s1_ = srcs[p+1], s2_ = srcs[p+2], s3_ = srcs[p+3];
    float l0 = a_s[(size_t)s0_*8 + head] + ad_h;
    float l1 = a_s[(size_t)s1_*8 + head] + ad_h;
    float l2 = a_s[(size_t)s2_*8 + head] + ad_h;
    float l3 = a_s[(size_t)s3_*8 + head] + ad_h;
    u16x8 v0 = *reinterpret_cast<const u16x8*>(feat + (size_t)s0_*512 + c0);
    u16x8 v1 = *reinterpret_cast<const u16x8*>(feat + (size_t)s1_*512 + c0);
    u16x8 v2 = *reinterpret_cast<const u16x8*>(feat + (size_t)s2_*512 + c0);
    u16x8 v3 = *reinterpret_cast<const u16x8*>(feat + (size_t)s3_*512 + c0);
    float al0 = expf((l0 > 0.f) ? l0 : NEG*l0);
    float al1 = expf((l1 > 0.f) ? l1 : NEG*l1);
    float al2 = expf((l2 > 0.f) ? l2 : NEG*l2);
    float al3 = expf((l3 > 0.f) ? l3 : NEG*l3);
    dsum += al0 + al1 + al2 + al3;
    #pragma unroll
    for(int j=0;j<8;j++) acc[j] += al0*b2f((ushortT)v0[j]);
    #pragma unroll
    for(int j=0;j<8;j++) acc[j] += al1*b2f((ushortT)v1[j]);
    #pragma unroll
    for(int j=0;j<8;j++) acc[j] += al2*b2f((ushortT)v2[j]);
    #pragma unroll
    for(int j=0;j<8;j++) acc[j] += al3*b2f((ushortT)v3[j]);
  }
  for(; p<p1; p++){
    int s_ = srcs[p];
    float l = a_s[(size_t)s_*8 + head] + ad_h;
    u16x8 v = *reinterpret_cast<const u16x8*>(feat + (size_t)s_*512 + c0);
    float al = expf((l > 0.f) ? l : NEG*l);
    dsum += al;
    #pragma unroll
    for(int j=0;j<8;j++) acc[j] += al*b2f((ushortT)v[j]);
  }
  float invd = 1.f/(dsum + 1e-16f);
  u16x8 ov;
  #pragma unroll
  for(int j=0;j<8;j++){
    float o = acc[j]*invd + bias[c0+j];
    o = (o > 0.f) ? o : (expf(o) - 1.f);
    ov[j] = f2b(o);
  }
  *reinterpret_cast<u16x8*>(outb + (size_t)d*512 + c0) = ov;
}

// ---------- layer-3 aggregate (H=1,C=40) fused softmax + bias + log_softmax ----------
__global__ void k_agg_l3(const float* __restrict__ feat,
    const float* __restrict__ a_s, const float* __restrict__ a_d,
    const int* __restrict__ rowstart, const int* __restrict__ srcs,
    const float* __restrict__ bias, float* __restrict__ outp){
  int d = blockIdx.x;
  int lane = threadIdx.x;       // 64 threads
  bool act = lane < 40;
  int li = act ? lane : 0;
  float ad_v = a_d[d];
  float acc = 0.f, dsum = 0.f;
  int p0 = rowstart[d], p1 = rowstart[d+1];
  int p = p0;
  for(; p+4 <= p1; p += 4){
    int s0_ = srcs[p], s1_ = srcs[p+1], s2_ = srcs[p+2], s3_ = srcs[p+3];
    float l0 = a_s[s0_] + ad_v, l1 = a_s[s1_] + ad_v;
    float l2 = a_s[s2_] + ad_v, l3 = a_s[s3_] + ad_v;
    float v0 = feat[(size_t)s0_*40 + li];
    float v1 = feat[(size_t)s1_*40 + li];
    float v2 = feat[(size_t)s2_*40 + li];
    float v3 = feat[(size_t)s3_*40 + li];
    float al0 = expf((l0 > 0.f) ? l0 : NEG*l0);
    float al1 = expf((l1 > 0.f) ? l1 : NEG*l1);
    float al2 = expf((l2 > 0.f) ? l2 : NEG*l2);
    float al3 = expf((l3 > 0.f) ? l3 : NEG*l3);
    dsum += al0 + al1 + al2 + al3;
    acc += al0*v0 + al1*v1 + al2*v2 + al3*v3;
  }
  for(; p<p1; p++){
    int s_ = srcs[p];
    float l = a_s[s_] + ad_v;
    float al = expf((l > 0.f) ? l : NEG*l);
    dsum += al;
    acc += al*feat[(size_t)s_*40 + li];
  }
  float invd = 1.f/(dsum + 1e-16f);
  float o = act ? (acc*invd + bias[lane]) : -1e30f;
  float m = o;
  for(int off=32; off; off>>=1) m = fmaxf(m, __shfl_xor(m, off));
  float e_ = act ? expf(o - m) : 0.f;
  float ssum = e_;
  for(int off=32; off; off>>=1) ssum += __shfl_xor(ssum, off);
  if(act) outp[(size_t)d*40 + lane] = o - m - logf(ssum);
}

extern "C" void kernel_launch(void* const* d_in, const int* in_sizes, int n_in,
                              void* d_out, int out_size, void* d_ws, size_t ws_size,
                              hipStream_t stream){
  const float* x   = (const float*)d_in[0];
  const int*   ei  = (const int*)d_in[1];
  const int*   esrc = ei;
  const int*   edst = ei + EE;
  const float* W1  = (const float*)d_in[2];
  const float* as1 = (const float*)d_in[3];
  const float* ad1 = (const float*)d_in[4];
  const float* b1  = (const float*)d_in[5];
  const float* W2  = (const float*)d_in[6];
  const float* as2 = (const float*)d_in[7];
  const float* ad2 = (const float*)d_in[8];
  const float* b2  = (const float*)d_in[9];
  const float* W3  = (const float*)d_in[10];
  const float* as3 = (const float*)d_in[11];
  const float* ad3 = (const float*)d_in[12];
  const float* b3  = (const float*)d_in[13];
  float* out = (float*)d_out;

  char* w = (char*)d_ws;
  size_t off = 0;
  auto alloc = [&](size_t bytes)->char*{
    char* p = w + off;
    off = (off + bytes + 255) & ~(size_t)255;
    return p;
  };
  ushortT*  xb   = (ushortT*)alloc((size_t)NN*512*2);
  ushortT*  fA   = (ushortT*)alloc((size_t)NN*512*2);
  ushortT*  fB   = (ushortT*)alloc((size_t)NN*512*2);
  float*    h3   = (float*)alloc((size_t)NN*40*4);
  ushortT*  Wt1  = (ushortT*)alloc((size_t)512*512*2);
  ushortT*  Wt2  = (ushortT*)alloc((size_t)512*512*2);
  float*    a_s  = (float*)alloc((size_t)NN*8*4);
  float*    a_d  = (float*)alloc((size_t)NN*8*4);
  int* rowstart  = (int*)alloc((size_t)(NN+1)*4);
  int* cursor    = (int*)alloc((size_t)NN*4);
  int* counts    = (int*)alloc((size_t)NN*4);
  int* srcs      = (int*)alloc((size_t)ETOT*4);

  // ---- conversions (independent of CSR) ----
  k_cvt<<<(NN*512/4 + 255)/256, 256, 0, stream>>>(x, xb, NN*512/4);
  dim3 wt_grid(16, 16);
  k_wtrans<<<wt_grid, 256, 0, stream>>>(W1, Wt1);
  k_wtrans<<<wt_grid, 256, 0, stream>>>(W2, Wt2);

  // ---- CSR build (dst-grouped) ----
  hipMemsetAsync(counts, 0, (size_t)NN*4, stream);
  hipMemsetAsync(cursor, 0, (size_t)NN*4, stream);
  k_count<<<(ETOT+255)/256, 256, 0, stream>>>(edst, counts);
  k_scan<<<1, 1024, 0, stream>>>(counts, rowstart);
  k_fill<<<(ETOT+255)/256, 256, 0, stream>>>(esrc, edst, rowstart, cursor, srcs);

  dim3 mgrid((NN+127)/128, 4);

  // ---- layer 1 ----
  k_gemm_bf16<<<mgrid, 256, 0, stream>>>(xb, Wt1, fA, NN);
  k_attn_b<8,64><<<(NN+3)/4, 256, 0, stream>>>(fA, as1, ad1, a_s, a_d);
  k_agg512<<<NN/4, 256, 0, stream>>>(fA, a_s, a_d, rowstart, srcs, b1, fB);

  // ---- layer 2 ----
  k_gemm_bf16<<<mgrid, 256, 0, stream>>>(fB, Wt2, fA, NN);
  k_attn_b<8,64><<<(NN+3)/4, 256, 0, stream>>>(fA, as2, ad2, a_s, a_d);
  k_agg512<<<NN/4, 256, 0, stream>>>(fA, a_s, a_d, rowstart, srcs, b2, fB);

  // ---- layer 3 ----
  dim3 gemm_grid3((NN+63)/64, 1);
  k_gemm3<<<gemm_grid3, 256, 0, stream>>>(fB, W3, h3, NN, 40);
  k_attn_f<1,40><<<(NN+3)/4, 256, 0, stream>>>(h3, as3, ad3, a_s, a_d);
  k_agg_l3<<<NN, 64, 0, stream>>>(h3, a_s, a_d, rowstart, srcs, b3, out);
}

// Round 6
// 312.211 us; speedup vs baseline: 2.0765x; 1.0711x over previous
//
#include <hip/hip_runtime.h>
#include <math.h>

#define NN 20000
#define EE 320000
#define ETOT (EE + NN)
#define NEG 0.2f

typedef unsigned short ushortT;
typedef __attribute__((ext_vector_type(8))) short short8v;       // 8 bf16 (4 VGPRs)
typedef __attribute__((ext_vector_type(8))) unsigned short u16x8;
typedef __attribute__((ext_vector_type(4))) float f32x4;

// ---------- helpers ----------
__device__ __forceinline__ ushortT f2b(float f){            // fp32 -> bf16 (RNE)
  unsigned u = __float_as_uint(f);
  u += 0x7FFFu + ((u >> 16) & 1u);
  return (ushortT)(u >> 16);
}
__device__ __forceinline__ float b2f(ushortT b){
  return __uint_as_float(((unsigned)b) << 16);
}

// ---------- conversions ----------
__global__ void k_cvt(const float* __restrict__ in, ushortT* __restrict__ outp, int n4){
  int i = blockIdx.x*blockDim.x + threadIdx.x;
  if(i < n4){
    float4 v = *reinterpret_cast<const float4*>(in + (size_t)i*4);
    ushort4 o;
    o.x = f2b(v.x); o.y = f2b(v.y); o.z = f2b(v.z); o.w = f2b(v.w);
    *reinterpret_cast<ushort4*>(outp + (size_t)i*4) = o;
  }
}

// W[k][n] 512x512 fp32 -> Wt[n][k] bf16
__global__ void k_wtrans(const float* __restrict__ W, ushortT* __restrict__ Wt){
  __shared__ float t[32][33];
  int bk = blockIdx.x*32, bn = blockIdx.y*32;
  int tx = threadIdx.x & 31, ty = threadIdx.x >> 5;
  for(int r=0;r<32;r+=8)
    t[ty+r][tx] = W[(size_t)(bk+ty+r)*512 + bn+tx];
  __syncthreads();
  for(int r=0;r<32;r+=8)
    Wt[(size_t)(bn+ty+r)*512 + bk+tx] = f2b(t[tx][ty+r]);
}

// W3[512][40] fp32 -> Wt3p packed bf16 [64 kslots][48 rows][8], zero-padded rows 40..47
__global__ void k_wtrans3(const float* __restrict__ W3, ushortT* __restrict__ Wt3p){
  int idx = blockIdx.x*blockDim.x + threadIdx.x;
  if(idx >= 64*48*8) return;
  int kslot = idx / 384;
  int rem = idx - kslot*384;
  int n = rem >> 3;
  int jj = rem & 7;
  int k = kslot*8 + jj;
  float v = (n < 40) ? W3[(size_t)k*40 + n] : 0.f;
  Wt3p[idx] = f2b(v);
}

// ---------- CSR build ----------
__global__ void k_count(const int* __restrict__ edst, int* __restrict__ counts){
  int e = blockIdx.x*blockDim.x + threadIdx.x;
  if(e < ETOT){
    int d = (e < EE) ? edst[e] : (e - EE);
    atomicAdd(&counts[d], 1);
  }
}

__global__ void k_scan(const int* __restrict__ counts, int* __restrict__ rowstart){
  __shared__ int lds[1024];
  int tid = threadIdx.x;
  int base = tid*20;
  int s = 0;
  for(int j=0;j<20;j++){ int i=base+j; if(i<NN) s += counts[i]; }
  lds[tid] = s; __syncthreads();
  for(int off=1; off<1024; off<<=1){
    int v = (tid>=off) ? lds[tid-off] : 0;
    __syncthreads();
    lds[tid] += v;
    __syncthreads();
  }
  int run = lds[tid] - s;
  for(int j=0;j<20;j++){
    int i = base+j;
    if(i <= NN){
      rowstart[i] = run;
      if(i < NN) run += counts[i];
    }
  }
}

__global__ void k_fill(const int* __restrict__ esrc, const int* __restrict__ edst,
                       const int* __restrict__ rowstart,
                       int* __restrict__ cursor, int* __restrict__ srcs){
  int e = blockIdx.x*blockDim.x + threadIdx.x;
  if(e < ETOT){
    int d = (e < EE) ? edst[e] : (e - EE);
    int s = (e < EE) ? esrc[e] : (e - EE);
    int pos = rowstart[d] + atomicAdd(&cursor[d], 1);
    srcs[pos] = s;
  }
}

// ---------- bf16 MFMA GEMM: C[M,512] = A[M,512] @ Bt[512,512]^T, bf16 out ----------
__global__ __launch_bounds__(256) void k_gemm_bf16(
    const ushortT* __restrict__ A, const ushortT* __restrict__ Bt,
    ushortT* __restrict__ Cb, int M)
{
  const int K = 512;
  __shared__ __align__(16) ushortT As[128*32];
  __shared__ __align__(16) ushortT Bs[128*32];
  int bm = blockIdx.x*128, bn = blockIdx.y*128;
  int tid = threadIdx.x, wave = tid>>6, lane = tid&63;
  int wm = (wave>>1)*64, wn = (wave&1)*64;
  f32x4 acc[4][4] = {};

  int l4 = lane>>2;
  int s4 = lane&3;
  int src_slot = s4 ^ (l4 & 3);     // XOR swizzle (both-sides involution)
  int r16 = lane&15, kg = lane>>4;

  for(int k0=0;k0<K;k0+=32){
    #pragma unroll
    for(int c=0;c<2;c++){
      int chunk = wave*2 + c;
      int arow = bm + chunk*16 + l4; if(arow > M-1) arow = M-1;
      const ushortT* ga = A + (size_t)arow*K + k0 + src_slot*8;
      __builtin_amdgcn_global_load_lds(
          (const __attribute__((address_space(1))) void*)ga,
          (__attribute__((address_space(3))) void*)(As + chunk*16*32), 16, 0, 0);
      int brow = bn + chunk*16 + l4;
      const ushortT* gb = Bt + (size_t)brow*K + k0 + src_slot*8;
      __builtin_amdgcn_global_load_lds(
          (const __attribute__((address_space(1))) void*)gb,
          (__attribute__((address_space(3))) void*)(Bs + chunk*16*32), 16, 0, 0);
    }
    asm volatile("s_waitcnt vmcnt(0)");
    __syncthreads();

    short8v a_frag[4], b_frag[4];
    #pragma unroll
    for(int i=0;i<4;i++){
      int row = wm + i*16 + r16;
      a_frag[i] = *reinterpret_cast<const short8v*>(As + row*32 + ((kg ^ (row&3))<<3));
    }
    #pragma unroll
    for(int j=0;j<4;j++){
      int row = wn + j*16 + r16;
      b_frag[j] = *reinterpret_cast<const short8v*>(Bs + row*32 + ((kg ^ (row&3))<<3));
    }
    #pragma unroll
    for(int i=0;i<4;i++)
      #pragma unroll
      for(int j=0;j<4;j++)
        acc[i][j] = __builtin_amdgcn_mfma_f32_16x16x32_bf16(a_frag[i], b_frag[j], acc[i][j], 0, 0, 0);
    __syncthreads();
  }

  // C/D layout: col = lane&15, row = (lane>>4)*4 + reg
  #pragma unroll
  for(int i=0;i<4;i++){
    #pragma unroll
    for(int j=0;j<4;j++){
      #pragma unroll
      for(int r=0;r<4;r++){
        int row = bm + wm + i*16 + kg*4 + r;
        int col = bn + wn + j*16 + r16;
        if(row < M) Cb[(size_t)row*512 + col] = f2b(acc[i][j][r]);
      }
    }
  }
}

// ---------- layer-3 MFMA GEMM: h3[M,40] = A[M,512] @ W3; B resident in LDS ----------
__global__ __launch_bounds__(256) void k_gemm3m(const ushortT* __restrict__ A,
                                                const ushortT* __restrict__ Wt3p,
                                                float* __restrict__ C, int M){
  const int K = 512;
  __shared__ __align__(16) ushortT As[128*32];      // 8 KB
  __shared__ __align__(16) ushortT Bs[64*48*8];     // 48 KB, [kslot][n][8]
  int bm = blockIdx.x*128;
  int tid = threadIdx.x, wave = tid>>6, lane = tid&63;

  // stage entire packed B once (24576 elems = 256 thr x 12 x u16x8)
  #pragma unroll
  for(int it=0; it<12; it++){
    int o = (it*256 + tid)*8;
    *reinterpret_cast<u16x8*>(Bs + o) = *reinterpret_cast<const u16x8*>(Wt3p + o);
  }

  int l4 = lane>>2, s4 = lane&3;
  int src_slot = s4 ^ (l4 & 3);
  int r16 = lane&15, kg = lane>>4;
  f32x4 acc[2][3] = {};

  for(int k0=0;k0<K;k0+=32){
    #pragma unroll
    for(int c=0;c<2;c++){
      int chunk = wave*2 + c;
      int arow = bm + chunk*16 + l4; if(arow > M-1) arow = M-1;
      const ushortT* ga = A + (size_t)arow*K + k0 + src_slot*8;
      __builtin_amdgcn_global_load_lds(
          (const __attribute__((address_space(1))) void*)ga,
          (__attribute__((address_space(3))) void*)(As + chunk*16*32), 16, 0, 0);
    }
    asm volatile("s_waitcnt vmcnt(0)");
    __syncthreads();

    short8v a_frag[2], b_frag[3];
    #pragma unroll
    for(int i=0;i<2;i++){
      int row = wave*32 + i*16 + r16;
      a_frag[i] = *reinterpret_cast<const short8v*>(As + row*32 + ((kg ^ (row&3))<<3));
    }
    int kslot = (k0>>3) + kg;
    #pragma unroll
    for(int j=0;j<3;j++){
      b_frag[j] = *reinterpret_cast<const short8v*>(Bs + kslot*384 + (j*16 + r16)*8);
    }
    #pragma unroll
    for(int i=0;i<2;i++)
      #pragma unroll
      for(int j=0;j<3;j++)
        acc[i][j] = __builtin_amdgcn_mfma_f32_16x16x32_bf16(a_frag[i], b_frag[j], acc[i][j], 0, 0, 0);
    __syncthreads();
  }

  #pragma unroll
  for(int i=0;i<2;i++){
    #pragma unroll
    for(int j=0;j<3;j++){
      #pragma unroll
      for(int r=0;r<4;r++){
        int row = bm + wave*32 + i*16 + kg*4 + r;
        int col = j*16 + r16;
        if(row < M && col < 40) C[(size_t)row*40 + col] = acc[i][j][r];
      }
    }
  }
}

// ---------- per-node attention coefficients (bf16 features) ----------
template<int H, int C>
__global__ void k_attn_b(const ushortT* __restrict__ feat, const float* __restrict__ atts,
                         const float* __restrict__ attd, float* __restrict__ a_s,
                         float* __restrict__ a_d){
  int n = blockIdx.x*4 + (threadIdx.x>>6);
  int lane = threadIdx.x & 63;
  if(n >= NN) return;
  #pragma unroll
  for(int h=0;h<H;h++){
    float s1 = 0.f, s2 = 0.f;
    if(lane < C){
      float v = b2f(feat[(size_t)n*(H*C) + h*C + lane]);
      s1 = v*atts[h*C+lane];
      s2 = v*attd[h*C+lane];
    }
    for(int off=32; off; off>>=1){
      s1 += __shfl_xor(s1, off);
      s2 += __shfl_xor(s2, off);
    }
    if(lane == 0){ a_s[n*H+h] = s1; a_d[n*H+h] = s2; }
  }
}

// fp32 features (layer 3)
template<int H, int C>
__global__ void k_attn_f(const float* __restrict__ feat, const float* __restrict__ atts,
                         const float* __restrict__ attd, float* __restrict__ a_s,
                         float* __restrict__ a_d){
  int n = blockIdx.x*4 + (threadIdx.x>>6);
  int lane = threadIdx.x & 63;
  if(n >= NN) return;
  #pragma unroll
  for(int h=0;h<H;h++){
    float s1 = 0.f, s2 = 0.f;
    if(lane < C){
      float v = feat[(size_t)n*(H*C) + h*C + lane];
      s1 = v*atts[h*C+lane];
      s2 = v*attd[h*C+lane];
    }
    for(int off=32; off; off>>=1){
      s1 += __shfl_xor(s1, off);
      s2 += __shfl_xor(s2, off);
    }
    if(lane == 0){ a_s[n*H+h] = s1; a_d[n*H+h] = s2; }
  }
}

// ---------- fused CSR aggregate (H=8,C=64), softmax on the fly ----------
// TWO waves per dst: wave handles 256 channels, lane owns 4 (8-B loads).
// 2x independent gather streams + 2x wave count vs one-wave-per-dst.
__global__ __launch_bounds__(256) void k_agg512(const ushortT* __restrict__ feat,
    const float* __restrict__ a_s, const float* __restrict__ a_d,
    const int* __restrict__ rowstart, const int* __restrict__ srcs,
    const float* __restrict__ bias, ushortT* __restrict__ outb){
  int wave = threadIdx.x>>6, lane = threadIdx.x&63;
  int d = blockIdx.x*2 + (wave>>1);
  int half = wave&1;
  int c0 = half*256 + lane*4;
  int head = c0>>6;
  float ad_h = a_d[(size_t)d*8 + head];
  float acc[4] = {0.f,0.f,0.f,0.f};
  float dsum = 0.f;
  int p0 = rowstart[d], p1 = rowstart[d+1];
  int p = p0;
  for(; p+4 <= p1; p += 4){
    int s0_ = srcs[p], s1_ = srcs[p+1], s2_ = srcs[p+2], s3_ = srcs[p+3];
    float l0 = a_s[(size_t)s0_*8 + head] + ad_h;
    float l1 = a_s[(size_t)s1_*8 + head] + ad_h;
    float l2 = a_s[(size_t)s2_*8 + head] + ad_h;
    float l3 = a_s[(size_t)s3_*8 + head] + ad_h;
    ushort4 v0 = *reinterpret_cast<const ushort4*>(feat + (size_t)s0_*512 + c0);
    ushort4 v1 = *reinterpret_cast<const ushort4*>(feat + (size_t)s1_*512 + c0);
    ushort4 v2 = *reinterpret_cast<const ushort4*>(feat + (size_t)s2_*512 + c0);
    ushort4 v3 = *reinterpret_cast<const ushort4*>(feat + (size_t)s3_*512 + c0);
    float al0 = expf((l0 > 0.f) ? l0 : NEG*l0);
    float al1 = expf((l1 > 0.f) ? l1 : NEG*l1);
    float al2 = expf((l2 > 0.f) ? l2 : NEG*l2);
    float al3 = expf((l3 > 0.f) ? l3 : NEG*l3);
    dsum += al0 + al1 + al2 + al3;
    acc[0] += al0*b2f(v0.x); acc[1] += al0*b2f(v0.y); acc[2] += al0*b2f(v0.z); acc[3] += al0*b2f(v0.w);
    acc[0] += al1*b2f(v1.x); acc[1] += al1*b2f(v1.y); acc[2] += al1*b2f(v1.z); acc[3] += al1*b2f(v1.w);
    acc[0] += al2*b2f(v2.x); acc[1] += al2*b2f(v2.y); acc[2] += al2*b2f(v2.z); acc[3] += al2*b2f(v2.w);
    acc[0] += al3*b2f(v3.x); acc[1] += al3*b2f(v3.y); acc[2] += al3*b2f(v3.z); acc[3] += al3*b2f(v3.w);
  }
  for(; p<p1; p++){
    int s_ = srcs[p];
    float l = a_s[(size_t)s_*8 + head] + ad_h;
    ushort4 v = *reinterpret_cast<const ushort4*>(feat + (size_t)s_*512 + c0);
    float al = expf((l > 0.f) ? l : NEG*l);
    dsum += al;
    acc[0] += al*b2f(v.x); acc[1] += al*b2f(v.y); acc[2] += al*b2f(v.z); acc[3] += al*b2f(v.w);
  }
  float invd = 1.f/(dsum + 1e-16f);
  ushort4 ov;
  float o0 = acc[0]*invd + bias[c0+0];
  float o1 = acc[1]*invd + bias[c0+1];
  float o2 = acc[2]*invd + bias[c0+2];
  float o3 = acc[3]*invd + bias[c0+3];
  o0 = (o0 > 0.f) ? o0 : (expf(o0) - 1.f);
  o1 = (o1 > 0.f) ? o1 : (expf(o1) - 1.f);
  o2 = (o2 > 0.f) ? o2 : (expf(o2) - 1.f);
  o3 = (o3 > 0.f) ? o3 : (expf(o3) - 1.f);
  ov.x = f2b(o0); ov.y = f2b(o1); ov.z = f2b(o2); ov.w = f2b(o3);
  *reinterpret_cast<ushort4*>(outb + (size_t)d*512 + c0) = ov;
}

// ---------- layer-3 aggregate (H=1,C=40) fused softmax + bias + log_softmax ----------
__global__ void k_agg_l3(const float* __restrict__ feat,
    const float* __restrict__ a_s, const float* __restrict__ a_d,
    const int* __restrict__ rowstart, const int* __restrict__ srcs,
    const float* __restrict__ bias, float* __restrict__ outp){
  int d = blockIdx.x;
  int lane = threadIdx.x;       // 64 threads
  bool act = lane < 40;
  int li = act ? lane : 0;
  float ad_v = a_d[d];
  float acc = 0.f, dsum = 0.f;
  int p0 = rowstart[d], p1 = rowstart[d+1];
  int p = p0;
  for(; p+4 <= p1; p += 4){
    int s0_ = srcs[p], s1_ = srcs[p+1], s2_ = srcs[p+2], s3_ = srcs[p+3];
    float l0 = a_s[s0_] + ad_v, l1 = a_s[s1_] + ad_v;
    float l2 = a_s[s2_] + ad_v, l3 = a_s[s3_] + ad_v;
    float v0 = feat[(size_t)s0_*40 + li];
    float v1 = feat[(size_t)s1_*40 + li];
    float v2 = feat[(size_t)s2_*40 + li];
    float v3 = feat[(size_t)s3_*40 + li];
    float al0 = expf((l0 > 0.f) ? l0 : NEG*l0);
    float al1 = expf((l1 > 0.f) ? l1 : NEG*l1);
    float al2 = expf((l2 > 0.f) ? l2 : NEG*l2);
    float al3 = expf((l3 > 0.f) ? l3 : NEG*l3);
    dsum += al0 + al1 + al2 + al3;
    acc += al0*v0 + al1*v1 + al2*v2 + al3*v3;
  }
  for(; p<p1; p++){
    int s_ = srcs[p];
    float l = a_s[s_] + ad_v;
    float al = expf((l > 0.f) ? l : NEG*l);
    dsum += al;
    acc += al*feat[(size_t)s_*40 + li];
  }
  float invd = 1.f/(dsum + 1e-16f);
  float o = act ? (acc*invd + bias[lane]) : -1e30f;
  float m = o;
  for(int off=32; off; off>>=1) m = fmaxf(m, __shfl_xor(m, off));
  float e_ = act ? expf(o - m) : 0.f;
  float ssum = e_;
  for(int off=32; off; off>>=1) ssum += __shfl_xor(ssum, off);
  if(act) outp[(size_t)d*40 + lane] = o - m - logf(ssum);
}

extern "C" void kernel_launch(void* const* d_in, const int* in_sizes, int n_in,
                              void* d_out, int out_size, void* d_ws, size_t ws_size,
                              hipStream_t stream){
  const float* x   = (const float*)d_in[0];
  const int*   ei  = (const int*)d_in[1];
  const int*   esrc = ei;
  const int*   edst = ei + EE;
  const float* W1  = (const float*)d_in[2];
  const float* as1 = (const float*)d_in[3];
  const float* ad1 = (const float*)d_in[4];
  const float* b1  = (const float*)d_in[5];
  const float* W2  = (const float*)d_in[6];
  const float* as2 = (const float*)d_in[7];
  const float* ad2 = (const float*)d_in[8];
  const float* b2  = (const float*)d_in[9];
  const float* W3  = (const float*)d_in[10];
  const float* as3 = (const float*)d_in[11];
  const float* ad3 = (const float*)d_in[12];
  const float* b3  = (const float*)d_in[13];
  float* out = (float*)d_out;

  char* w = (char*)d_ws;
  size_t off = 0;
  auto alloc = [&](size_t bytes)->char*{
    char* p = w + off;
    off = (off + bytes + 255) & ~(size_t)255;
    return p;
  };
  ushortT*  xb   = (ushortT*)alloc((size_t)NN*512*2);
  ushortT*  fA   = (ushortT*)alloc((size_t)NN*512*2);
  ushortT*  fB   = (ushortT*)alloc((size_t)NN*512*2);
  float*    h3   = (float*)alloc((size_t)NN*40*4);
  ushortT*  Wt1  = (ushortT*)alloc((size_t)512*512*2);
  ushortT*  Wt2  = (ushortT*)alloc((size_t)512*512*2);
  ushortT*  Wt3p = (ushortT*)alloc((size_t)64*48*8*2);
  float*    a_s  = (float*)alloc((size_t)NN*8*4);
  float*    a_d  = (float*)alloc((size_t)NN*8*4);
  int* rowstart  = (int*)alloc((size_t)(NN+1)*4);
  int* cursor    = (int*)alloc((size_t)NN*4);
  int* counts    = (int*)alloc((size_t)NN*4);
  int* srcs      = (int*)alloc((size_t)ETOT*4);

  // ---- conversions (independent of CSR) ----
  k_cvt<<<(NN*512/4 + 255)/256, 256, 0, stream>>>(x, xb, NN*512/4);
  dim3 wt_grid(16, 16);
  k_wtrans<<<wt_grid, 256, 0, stream>>>(W1, Wt1);
  k_wtrans<<<wt_grid, 256, 0, stream>>>(W2, Wt2);
  k_wtrans3<<<(64*48*8 + 255)/256, 256, 0, stream>>>(W3, Wt3p);

  // ---- CSR build (dst-grouped) ----
  hipMemsetAsync(counts, 0, (size_t)NN*4, stream);
  hipMemsetAsync(cursor, 0, (size_t)NN*4, stream);
  k_count<<<(ETOT+255)/256, 256, 0, stream>>>(edst, counts);
  k_scan<<<1, 1024, 0, stream>>>(counts, rowstart);
  k_fill<<<(ETOT+255)/256, 256, 0, stream>>>(esrc, edst, rowstart, cursor, srcs);

  dim3 mgrid((NN+127)/128, 4);

  // ---- layer 1 ----
  k_gemm_bf16<<<mgrid, 256, 0, stream>>>(xb, Wt1, fA, NN);
  k_attn_b<8,64><<<(NN+3)/4, 256, 0, stream>>>(fA, as1, ad1, a_s, a_d);
  k_agg512<<<NN/2, 256, 0, stream>>>(fA, a_s, a_d, rowstart, srcs, b1, fB);

  // ---- layer 2 ----
  k_gemm_bf16<<<mgrid, 256, 0, stream>>>(fB, Wt2, fA, NN);
  k_attn_b<8,64><<<(NN+3)/4, 256, 0, stream>>>(fA, as2, ad2, a_s, a_d);
  k_agg512<<<NN/2, 256, 0, stream>>>(fA, a_s, a_d, rowstart, srcs, b2, fB);

  // ---- layer 3 ----
  k_gemm3m<<<(NN+127)/128, 256, 0, stream>>>(fB, Wt3p, h3, NN);
  k_attn_f<1,40><<<(NN+3)/4, 256, 0, stream>>>(h3, as3, ad3, a_s, a_d);
  k_agg_l3<<<NN, 64, 0, stream>>>(h3, a_s, a_d, rowstart, srcs, b3, out);
}

// Round 7
// 272.257 us; speedup vs baseline: 2.3812x; 1.1467x over previous
//
#include <hip/hip_runtime.h>
#include <math.h>

#define NN 20000
#define EE 320000
#define ETOT (EE + NN)
#define NEG 0.2f

typedef unsigned short ushortT;
typedef __attribute__((ext_vector_type(8))) short short8v;       // 8 bf16 (4 VGPRs)
typedef __attribute__((ext_vector_type(8))) unsigned short u16x8;
typedef __attribute__((ext_vector_type(4))) float f32x4;

// ---------- helpers ----------
__device__ __forceinline__ ushortT f2b(float f){            // fp32 -> bf16 (RNE)
  unsigned u = __float_as_uint(f);
  u += 0x7FFFu + ((u >> 16) & 1u);
  return (ushortT)(u >> 16);
}
__device__ __forceinline__ float b2f(ushortT b){
  return __uint_as_float(((unsigned)b) << 16);
}

// ---------- conversions ----------
__global__ void k_cvt(const float* __restrict__ in, ushortT* __restrict__ outp, int n4){
  int i = blockIdx.x*blockDim.x + threadIdx.x;
  if(i < n4){
    float4 v = *reinterpret_cast<const float4*>(in + (size_t)i*4);
    ushort4 o;
    o.x = f2b(v.x); o.y = f2b(v.y); o.z = f2b(v.z); o.w = f2b(v.w);
    *reinterpret_cast<ushort4*>(outp + (size_t)i*4) = o;
  }
}

// W[k][n] 512x512 fp32 -> Wt[n][k] bf16
__global__ void k_wtrans(const float* __restrict__ W, ushortT* __restrict__ Wt){
  __shared__ float t[32][33];
  int bk = blockIdx.x*32, bn = blockIdx.y*32;
  int tx = threadIdx.x & 31, ty = threadIdx.x >> 5;
  for(int r=0;r<32;r+=8)
    t[ty+r][tx] = W[(size_t)(bk+ty+r)*512 + bn+tx];
  __syncthreads();
  for(int r=0;r<32;r+=8)
    Wt[(size_t)(bn+ty+r)*512 + bk+tx] = f2b(t[tx][ty+r]);
}

// W3[512][40] fp32 -> Wt3p packed bf16 [64 kslots][48 rows][8], zero-padded rows 40..47
__global__ void k_wtrans3(const float* __restrict__ W3, ushortT* __restrict__ Wt3p){
  int idx = blockIdx.x*blockDim.x + threadIdx.x;
  if(idx >= 64*48*8) return;
  int kslot = idx / 384;
  int rem = idx - kslot*384;
  int n = rem >> 3;
  int jj = rem & 7;
  int k = kslot*8 + jj;
  float v = (n < 40) ? W3[(size_t)k*40 + n] : 0.f;
  Wt3p[idx] = f2b(v);
}

// ---------- CSR build ----------
__global__ void k_count(const int* __restrict__ edst, int* __restrict__ counts){
  int e = blockIdx.x*blockDim.x + threadIdx.x;
  if(e < ETOT){
    int d = (e < EE) ? edst[e] : (e - EE);
    atomicAdd(&counts[d], 1);
  }
}

__global__ void k_scan(const int* __restrict__ counts, int* __restrict__ rowstart){
  __shared__ int lds[1024];
  int tid = threadIdx.x;
  int base = tid*20;
  int s = 0;
  for(int j=0;j<20;j++){ int i=base+j; if(i<NN) s += counts[i]; }
  lds[tid] = s; __syncthreads();
  for(int off=1; off<1024; off<<=1){
    int v = (tid>=off) ? lds[tid-off] : 0;
    __syncthreads();
    lds[tid] += v;
    __syncthreads();
  }
  int run = lds[tid] - s;
  for(int j=0;j<20;j++){
    int i = base+j;
    if(i <= NN){
      rowstart[i] = run;
      if(i < NN) run += counts[i];
    }
  }
}

__global__ void k_fill(const int* __restrict__ esrc, const int* __restrict__ edst,
                       const int* __restrict__ rowstart,
                       int* __restrict__ cursor, int* __restrict__ srcs){
  int e = blockIdx.x*blockDim.x + threadIdx.x;
  if(e < ETOT){
    int d = (e < EE) ? edst[e] : (e - EE);
    int s = (e < EE) ? esrc[e] : (e - EE);
    int pos = rowstart[d] + atomicAdd(&cursor[d], 1);
    srcs[pos] = s;
  }
}

// ---------- bf16 MFMA GEMM: C[M,512] = A[M,512] @ Bt[512,512]^T, bf16 out ----------
__global__ __launch_bounds__(256) void k_gemm_bf16(
    const ushortT* __restrict__ A, const ushortT* __restrict__ Bt,
    ushortT* __restrict__ Cb, int M)
{
  const int K = 512;
  __shared__ __align__(16) ushortT As[128*32];
  __shared__ __align__(16) ushortT Bs[128*32];
  int bm = blockIdx.x*128, bn = blockIdx.y*128;
  int tid = threadIdx.x, wave = tid>>6, lane = tid&63;
  int wm = (wave>>1)*64, wn = (wave&1)*64;
  f32x4 acc[4][4] = {};

  int l4 = lane>>2;
  int s4 = lane&3;
  int src_slot = s4 ^ (l4 & 3);     // XOR swizzle (both-sides involution)
  int r16 = lane&15, kg = lane>>4;

  for(int k0=0;k0<K;k0+=32){
    #pragma unroll
    for(int c=0;c<2;c++){
      int chunk = wave*2 + c;
      int arow = bm + chunk*16 + l4; if(arow > M-1) arow = M-1;
      const ushortT* ga = A + (size_t)arow*K + k0 + src_slot*8;
      __builtin_amdgcn_global_load_lds(
          (const __attribute__((address_space(1))) void*)ga,
          (__attribute__((address_space(3))) void*)(As + chunk*16*32), 16, 0, 0);
      int brow = bn + chunk*16 + l4;
      const ushortT* gb = Bt + (size_t)brow*K + k0 + src_slot*8;
      __builtin_amdgcn_global_load_lds(
          (const __attribute__((address_space(1))) void*)gb,
          (__attribute__((address_space(3))) void*)(Bs + chunk*16*32), 16, 0, 0);
    }
    asm volatile("s_waitcnt vmcnt(0)");
    __syncthreads();

    short8v a_frag[4], b_frag[4];
    #pragma unroll
    for(int i=0;i<4;i++){
      int row = wm + i*16 + r16;
      a_frag[i] = *reinterpret_cast<const short8v*>(As + row*32 + ((kg ^ (row&3))<<3));
    }
    #pragma unroll
    for(int j=0;j<4;j++){
      int row = wn + j*16 + r16;
      b_frag[j] = *reinterpret_cast<const short8v*>(Bs + row*32 + ((kg ^ (row&3))<<3));
    }
    #pragma unroll
    for(int i=0;i<4;i++)
      #pragma unroll
      for(int j=0;j<4;j++)
        acc[i][j] = __builtin_amdgcn_mfma_f32_16x16x32_bf16(a_frag[i], b_frag[j], acc[i][j], 0, 0, 0);
    __syncthreads();
  }

  // C/D layout: col = lane&15, row = (lane>>4)*4 + reg
  #pragma unroll
  for(int i=0;i<4;i++){
    #pragma unroll
    for(int j=0;j<4;j++){
      #pragma unroll
      for(int r=0;r<4;r++){
        int row = bm + wm + i*16 + kg*4 + r;
        int col = bn + wn + j*16 + r16;
        if(row < M) Cb[(size_t)row*512 + col] = f2b(acc[i][j][r]);
      }
    }
  }
}

// ---------- layer-3 MFMA GEMM: h3[M,40] = A[M,512] @ W3; B resident in LDS ----------
__global__ __launch_bounds__(256) void k_gemm3m(const ushortT* __restrict__ A,
                                                const ushortT* __restrict__ Wt3p,
                                                float* __restrict__ C, int M){
  const int K = 512;
  __shared__ __align__(16) ushortT As[128*32];      // 8 KB
  __shared__ __align__(16) ushortT Bs[64*48*8];     // 48 KB, [kslot][n][8]
  int bm = blockIdx.x*128;
  int tid = threadIdx.x, wave = tid>>6, lane = tid&63;

  // stage entire packed B once
  #pragma unroll
  for(int it=0; it<12; it++){
    int o = (it*256 + tid)*8;
    *reinterpret_cast<u16x8*>(Bs + o) = *reinterpret_cast<const u16x8*>(Wt3p + o);
  }

  int l4 = lane>>2, s4 = lane&3;
  int src_slot = s4 ^ (l4 & 3);
  int r16 = lane&15, kg = lane>>4;
  f32x4 acc[2][3] = {};

  for(int k0=0;k0<K;k0+=32){
    #pragma unroll
    for(int c=0;c<2;c++){
      int chunk = wave*2 + c;
      int arow = bm + chunk*16 + l4; if(arow > M-1) arow = M-1;
      const ushortT* ga = A + (size_t)arow*K + k0 + src_slot*8;
      __builtin_amdgcn_global_load_lds(
          (const __attribute__((address_space(1))) void*)ga,
          (__attribute__((address_space(3))) void*)(As + chunk*16*32), 16, 0, 0);
    }
    asm volatile("s_waitcnt vmcnt(0)");
    __syncthreads();

    short8v a_frag[2], b_frag[3];
    #pragma unroll
    for(int i=0;i<2;i++){
      int row = wave*32 + i*16 + r16;
      a_frag[i] = *reinterpret_cast<const short8v*>(As + row*32 + ((kg ^ (row&3))<<3));
    }
    int kslot = (k0>>3) + kg;
    #pragma unroll
    for(int j=0;j<3;j++){
      b_frag[j] = *reinterpret_cast<const short8v*>(Bs + kslot*384 + (j*16 + r16)*8);
    }
    #pragma unroll
    for(int i=0;i<2;i++)
      #pragma unroll
      for(int j=0;j<3;j++)
        acc[i][j] = __builtin_amdgcn_mfma_f32_16x16x32_bf16(a_frag[i], b_frag[j], acc[i][j], 0, 0, 0);
    __syncthreads();
  }

  #pragma unroll
  for(int i=0;i<2;i++){
    #pragma unroll
    for(int j=0;j<3;j++){
      #pragma unroll
      for(int r=0;r<4;r++){
        int row = bm + wave*32 + i*16 + kg*4 + r;
        int col = j*16 + r16;
        if(row < M && col < 40) C[(size_t)row*40 + col] = acc[i][j][r];
      }
    }
  }
}

// ---------- per-node attention coefficients, H=8 C=64 (bf16 features) ----------
// one WAVE per node: lane owns 8 contiguous channels (whole row in one u16x8),
// 3-hop shfl reduce within each 8-lane head group.
__global__ void k_attn8(const ushortT* __restrict__ feat, const float* __restrict__ atts,
                        const float* __restrict__ attd, float* __restrict__ a_s,
                        float* __restrict__ a_d){
  int n = blockIdx.x*4 + (threadIdx.x>>6);
  int lane = threadIdx.x & 63;
  if(n >= NN) return;
  int c0 = lane*8;
  u16x8 v = *reinterpret_cast<const u16x8*>(feat + (size_t)n*512 + c0);
  float s1 = 0.f, s2 = 0.f;
  #pragma unroll
  for(int j=0;j<8;j++){
    float f = b2f((ushortT)v[j]);
    s1 += f*atts[c0+j];
    s2 += f*attd[c0+j];
  }
  #pragma unroll
  for(int off=1; off<8; off<<=1){
    s1 += __shfl_xor(s1, off);
    s2 += __shfl_xor(s2, off);
  }
  if((lane&7) == 0){
    int head = lane>>3;
    a_s[n*8+head] = s1;
    a_d[n*8+head] = s2;
  }
}

// fp32 features (layer 3)
template<int H, int C>
__global__ void k_attn_f(const float* __restrict__ feat, const float* __restrict__ atts,
                         const float* __restrict__ attd, float* __restrict__ a_s,
                         float* __restrict__ a_d){
  int n = blockIdx.x*4 + (threadIdx.x>>6);
  int lane = threadIdx.x & 63;
  if(n >= NN) return;
  #pragma unroll
  for(int h=0;h<H;h++){
    float s1 = 0.f, s2 = 0.f;
    if(lane < C){
      float v = feat[(size_t)n*(H*C) + h*C + lane];
      s1 = v*atts[h*C+lane];
      s2 = v*attd[h*C+lane];
    }
    for(int off=32; off; off>>=1){
      s1 += __shfl_xor(s1, off);
      s2 += __shfl_xor(s2, off);
    }
    if(lane == 0){ a_s[n*H+h] = s1; a_d[n*H+h] = s2; }
  }
}

// ---------- fused CSR aggregate (H=8,C=64), softmax on the fly ----------
// ONE wave per dst; lane owns 8 contiguous channels (16B loads); head = lane>>3.
// 8-deep / 4-deep / scalar pipeline, fast exp, max-form leaky, 32-bit offsets.
__global__ __launch_bounds__(256) void k_agg512(const ushortT* __restrict__ feat,
    const float* __restrict__ a_s, const float* __restrict__ a_d,
    const int* __restrict__ rowstart, const int* __restrict__ srcs,
    const float* __restrict__ bias, ushortT* __restrict__ outb){
  int d = blockIdx.x*4 + (threadIdx.x>>6);
  int lane = threadIdx.x & 63;
  unsigned c0 = (unsigned)lane*8u;
  int head = lane>>3;
  float ad_h = a_d[(size_t)d*8 + head];
  float acc[8] = {0.f,0.f,0.f,0.f,0.f,0.f,0.f,0.f};
  float dsum = 0.f;
  int p0 = rowstart[d], p1 = rowstart[d+1];
  int p = p0;

  for(; p+8 <= p1; p += 8){
    int   ss[8];
    float ll[8];
    u16x8 vv[8];
    #pragma unroll
    for(int q=0;q<8;q++) ss[q] = srcs[p+q];
    #pragma unroll
    for(int q=0;q<8;q++) ll[q] = a_s[((unsigned)ss[q]<<3) + (unsigned)head];
    #pragma unroll
    for(int q=0;q<8;q++) vv[q] = *reinterpret_cast<const u16x8*>(feat + (((unsigned)ss[q]<<9) + c0));
    #pragma unroll
    for(int q=0;q<8;q++){
      float l  = ll[q] + ad_h;
      float al = __expf(fmaxf(l, NEG*l));
      dsum += al;
      #pragma unroll
      for(int j=0;j<8;j++) acc[j] += al*b2f((ushortT)vv[q][j]);
    }
  }
  for(; p+4 <= p1; p += 4){
    int   ss[4];
    float ll[4];
    u16x8 vv[4];
    #pragma unroll
    for(int q=0;q<4;q++) ss[q] = srcs[p+q];
    #pragma unroll
    for(int q=0;q<4;q++) ll[q] = a_s[((unsigned)ss[q]<<3) + (unsigned)head];
    #pragma unroll
    for(int q=0;q<4;q++) vv[q] = *reinterpret_cast<const u16x8*>(feat + (((unsigned)ss[q]<<9) + c0));
    #pragma unroll
    for(int q=0;q<4;q++){
      float l  = ll[q] + ad_h;
      float al = __expf(fmaxf(l, NEG*l));
      dsum += al;
      #pragma unroll
      for(int j=0;j<8;j++) acc[j] += al*b2f((ushortT)vv[q][j]);
    }
  }
  for(; p<p1; p++){
    int s_ = srcs[p];
    float l = a_s[((unsigned)s_<<3) + (unsigned)head] + ad_h;
    u16x8 v = *reinterpret_cast<const u16x8*>(feat + (((unsigned)s_<<9) + c0));
    float al = __expf(fmaxf(l, NEG*l));
    dsum += al;
    #pragma unroll
    for(int j=0;j<8;j++) acc[j] += al*b2f((ushortT)v[j]);
  }

  float invd = 1.f/(dsum + 1e-16f);
  u16x8 ov;
  #pragma unroll
  for(int j=0;j<8;j++){
    float o = acc[j]*invd + bias[c0+j];
    o = (o > 0.f) ? o : (__expf(o) - 1.f);
    ov[j] = f2b(o);
  }
  *reinterpret_cast<u16x8*>(outb + (size_t)d*512 + c0) = ov;
}

// ---------- layer-3 aggregate (H=1,C=40) fused softmax + bias + log_softmax ----------
__global__ void k_agg_l3(const float* __restrict__ feat,
    const float* __restrict__ a_s, const float* __restrict__ a_d,
    const int* __restrict__ rowstart, const int* __restrict__ srcs,
    const float* __restrict__ bias, float* __restrict__ outp){
  int d = blockIdx.x;
  int lane = threadIdx.x;       // 64 threads
  bool act = lane < 40;
  int li = act ? lane : 0;
  float ad_v = a_d[d];
  float acc = 0.f, dsum = 0.f;
  int p0 = rowstart[d], p1 = rowstart[d+1];
  int p = p0;
  for(; p+4 <= p1; p += 4){
    int s0_ = srcs[p], s1_ = srcs[p+1], s2_ = srcs[p+2], s3_ = srcs[p+3];
    float l0 = a_s[s0_] + ad_v, l1 = a_s[s1_] + ad_v;
    float l2 = a_s[s2_] + ad_v, l3 = a_s[s3_] + ad_v;
    float v0 = feat[(size_t)s0_*40 + li];
    float v1 = feat[(size_t)s1_*40 + li];
    float v2 = feat[(size_t)s2_*40 + li];
    float v3 = feat[(size_t)s3_*40 + li];
    float al0 = __expf(fmaxf(l0, NEG*l0));
    float al1 = __expf(fmaxf(l1, NEG*l1));
    float al2 = __expf(fmaxf(l2, NEG*l2));
    float al3 = __expf(fmaxf(l3, NEG*l3));
    dsum += al0 + al1 + al2 + al3;
    acc += al0*v0 + al1*v1 + al2*v2 + al3*v3;
  }
  for(; p<p1; p++){
    int s_ = srcs[p];
    float l = a_s[s_] + ad_v;
    float al = __expf(fmaxf(l, NEG*l));
    dsum += al;
    acc += al*feat[(size_t)s_*40 + li];
  }
  float invd = 1.f/(dsum + 1e-16f);
  float o = act ? (acc*invd + bias[lane]) : -1e30f;
  float m = o;
  for(int off=32; off; off>>=1) m = fmaxf(m, __shfl_xor(m, off));
  float e_ = act ? expf(o - m) : 0.f;
  float ssum = e_;
  for(int off=32; off; off>>=1) ssum += __shfl_xor(ssum, off);
  if(act) outp[(size_t)d*40 + lane] = o - m - logf(ssum);
}

extern "C" void kernel_launch(void* const* d_in, const int* in_sizes, int n_in,
                              void* d_out, int out_size, void* d_ws, size_t ws_size,
                              hipStream_t stream){
  const float* x   = (const float*)d_in[0];
  const int*   ei  = (const int*)d_in[1];
  const int*   esrc = ei;
  const int*   edst = ei + EE;
  const float* W1  = (const float*)d_in[2];
  const float* as1 = (const float*)d_in[3];
  const float* ad1 = (const float*)d_in[4];
  const float* b1  = (const float*)d_in[5];
  const float* W2  = (const float*)d_in[6];
  const float* as2 = (const float*)d_in[7];
  const float* ad2 = (const float*)d_in[8];
  const float* b2  = (const float*)d_in[9];
  const float* W3  = (const float*)d_in[10];
  const float* as3 = (const float*)d_in[11];
  const float* ad3 = (const float*)d_in[12];
  const float* b3  = (const float*)d_in[13];
  float* out = (float*)d_out;

  char* w = (char*)d_ws;
  size_t off = 0;
  auto alloc = [&](size_t bytes)->char*{
    char* p = w + off;
    off = (off + bytes + 255) & ~(size_t)255;
    return p;
  };
  ushortT*  xb   = (ushortT*)alloc((size_t)NN*512*2);
  ushortT*  fA   = (ushortT*)alloc((size_t)NN*512*2);
  ushortT*  fB   = (ushortT*)alloc((size_t)NN*512*2);
  float*    h3   = (float*)alloc((size_t)NN*40*4);
  ushortT*  Wt1  = (ushortT*)alloc((size_t)512*512*2);
  ushortT*  Wt2  = (ushortT*)alloc((size_t)512*512*2);
  ushortT*  Wt3p = (ushortT*)alloc((size_t)64*48*8*2);
  float*    a_s  = (float*)alloc((size_t)NN*8*4);
  float*    a_d  = (float*)alloc((size_t)NN*8*4);
  int* rowstart  = (int*)alloc((size_t)(NN+1)*4);
  int* cursor    = (int*)alloc((size_t)NN*4);
  int* counts    = (int*)alloc((size_t)NN*4);
  int* srcs      = (int*)alloc((size_t)ETOT*4);

  // ---- conversions (independent of CSR) ----
  k_cvt<<<(NN*512/4 + 255)/256, 256, 0, stream>>>(x, xb, NN*512/4);
  dim3 wt_grid(16, 16);
  k_wtrans<<<wt_grid, 256, 0, stream>>>(W1, Wt1);
  k_wtrans<<<wt_grid, 256, 0, stream>>>(W2, Wt2);
  k_wtrans3<<<(64*48*8 + 255)/256, 256, 0, stream>>>(W3, Wt3p);

  // ---- CSR build (dst-grouped) ----
  hipMemsetAsync(counts, 0, (size_t)NN*4, stream);
  hipMemsetAsync(cursor, 0, (size_t)NN*4, stream);
  k_count<<<(ETOT+255)/256, 256, 0, stream>>>(edst, counts);
  k_scan<<<1, 1024, 0, stream>>>(counts, rowstart);
  k_fill<<<(ETOT+255)/256, 256, 0, stream>>>(esrc, edst, rowstart, cursor, srcs);

  dim3 mgrid((NN+127)/128, 4);

  // ---- layer 1 ----
  k_gemm_bf16<<<mgrid, 256, 0, stream>>>(xb, Wt1, fA, NN);
  k_attn8<<<(NN+3)/4, 256, 0, stream>>>(fA, as1, ad1, a_s, a_d);
  k_agg512<<<NN/4, 256, 0, stream>>>(fA, a_s, a_d, rowstart, srcs, b1, fB);

  // ---- layer 2 ----
  k_gemm_bf16<<<mgrid, 256, 0, stream>>>(fB, Wt2, fA, NN);
  k_attn8<<<(NN+3)/4, 256, 0, stream>>>(fA, as2, ad2, a_s, a_d);
  k_agg512<<<NN/4, 256, 0, stream>>>(fA, a_s, a_d, rowstart, srcs, b2, fB);

  // ---- layer 3 ----
  k_gemm3m<<<(NN+127)/128, 256, 0, stream>>>(fB, Wt3p, h3, NN);
  k_attn_f<1,40><<<(NN+3)/4, 256, 0, stream>>>(h3, as3, ad3, a_s, a_d);
  k_agg_l3<<<NN, 64, 0, stream>>>(h3, a_s, a_d, rowstart, srcs, b3, out);
}